// Round 9
// baseline (169.827 us; speedup 1.0000x reference)
//
#include <hip/hip_runtime.h>
#include <stdint.h>

#define N 1024
#define BATCH 32
#define NFILL 1216          // fill blocks; 1216 * 27 rows = 32832 >= 32768 rows
#define ROWS_PER_FILL 27    // 27 rows * 4 KiB = 108 KiB span per fill block
#define TOTROWS (BATCH * N) // 32768 output rows

// ---------------------------------------------------------------------------
// Init: zero the rank-completion counter (workspace is re-poisoned each
// iteration with unknown bytes). Tiny; replaces the scatter launch.
// ---------------------------------------------------------------------------
__global__ __launch_bounds__(64) void init_kernel(int* __restrict__ counter) {
    if (threadIdx.x == 0) *counter = 0;
}

// ---------------------------------------------------------------------------
// Fused kernel — single pass over the output, deadlock-safe by CAPACITY.
//   Grid = 32 rank + 1216 fill = 1248 blocks; LDS ~28.9 KiB -> 5 blocks/CU
//   -> 1280 co-resident >= 1248, so ALL blocks run concurrently regardless
//   of dispatch order (G16: order is undefined; we rely only on capacity).
//
//   Rank blocks [0,32): verified R3/R8 pipeline, arithmetic untouched.
//     After writing ranks (4 KB/block): __syncthreads (drains stores), then
//     thread 0 does ONE agent-scope RELEASE atomicAdd. Only 32 releases of
//     4 KB dirty each — the R2 disaster (1024 heavy-store producers each
//     draining full dirty L2s) is inverted: heavy-store blocks never fence.
//
//   Fill blocks [32,1248): own 27 output rows (108 KiB). Zero them with
//     plain cached dwordx4 stores (R8 A/B: plain > NT by ~3 us), then
//     __syncthreads (zeros complete in L2), then acquire-poll the counter
//     until all 32 rank blocks released, then write the <=2 nonzeros for
//     each owned row. Nonzero lines are still resident in this XCD's L2
//     (just zeroed by this block) -> no RMW fetch from HBM, and no dirty-L2
//     kernel boundary between zeros and scatter.
// ---------------------------------------------------------------------------
__global__ __launch_bounds__(256) void fused_kernel(const float* __restrict__ x,
                                                    float* __restrict__ out,
                                                    float* __restrict__ ranks,
                                                    int* __restrict__ counter) {
    const int t = threadIdx.x;

    if (blockIdx.x >= BATCH) {
        // ---- fill branch: zero 27 rows, then scatter their nonzeros -------
        const int fid   = blockIdx.x - BATCH;
        const int rb    = fid * ROWS_PER_FILL;            // first owned row
        const int nrows = min(ROWS_PER_FILL, TOTROWS - rb);
        if (nrows <= 0) return;

        float4* o = reinterpret_cast<float4*>(out) + (size_t)rb * 256 + t;
        const float4 z = make_float4(0.0f, 0.0f, 0.0f, 0.0f);
        #pragma unroll 4
        for (int k = 0; k < nrows; ++k)
            o[k * 256] = z;

        __syncthreads();   // compiler drains vmcnt(0) -> zeros complete in L2

        if (t == 0) {
            while (__hip_atomic_load(counter, __ATOMIC_ACQUIRE,
                                     __HIP_MEMORY_SCOPE_AGENT) < BATCH)
                __builtin_amdgcn_s_sleep(32);
        }
        __syncthreads();

        if (t < nrows) {
            const int   row  = rb + t;
            const float r    = ranks[row];
            const float f    = floorf(r);
            const int   i1   = (int)f;       // nonzeros at i+1 == i1, i1+1
            const float frac = r - f;
            float* orow = out + (size_t)row * N;
            if (i1 >= 1 && i1 <= N) orow[i1 - 1] = 1.0f - frac;
            if (i1 >= 0 && i1 <  N) orow[i1]     = frac;
        }
        return;
    }

    // ---- rank branch (one block per batch row) ----------------------------
    // Region A (8K): keys (u64, phase 1) -> csum (double, phase 2b+).
    // Region B (4K): ss (phase 1-2a) -> yv in-place (2a-2b) -> run_mean (PAV+).
    __shared__ double   regA[N];
    __shared__ float    regB[N];
    __shared__ uint16_t segid[N];       // run id per sorted position (<=1023)
    __shared__ uint16_t run_start[N+1]; // run boundary positions (<=1024)
    __shared__ double   stk_sum[N];     // PAV stack: block sums
    __shared__ uint32_t stk_cr[N];      // PAV stack: cnt (low16) | runs (high16)
    __shared__ double   wsumD[4];
    __shared__ int      wsumI[4];

    uint64_t* keys     = reinterpret_cast<uint64_t*>(regA);
    double*   csum     = regA;
    float*    ss       = regB;
    float*    yv       = regB;
    float*    run_mean = regB;

    const int b = blockIdx.x;
    const int j0 = t << 2;
    const int lane = t & 63;
    const int wid = t >> 6;

    // ---- phase 1: load row, build keys, count positions in-block ----------
    const float4 xq = reinterpret_cast<const float4*>(x + b * N)[t];
    const float vv[4] = {xq.x, xq.y, xq.z, xq.w};
    uint64_t kk[4];
    {
        #pragma unroll
        for (int e = 0; e < 4; ++e) {
            uint32_t u = __float_as_uint(vv[e]);
            u ^= (u & 0x80000000u) ? 0xFFFFFFFFu : 0x80000000u;  // monotone map
            // descending, stable: position = #{k : key_k > key_j}
            kk[e] = (((uint64_t)u) << 10) | (uint64_t)(1023 - (j0 + e));
            keys[j0 + e] = kk[e];
        }
    }
    __syncthreads();

    int c[4] = {0, 0, 0, 0};
    for (int k = 0; k < N; k += 4) {
        const uint64_t k0 = keys[k];       // broadcast reads, conflict-free
        const uint64_t k1 = keys[k + 1];
        const uint64_t k2 = keys[k + 2];
        const uint64_t k3 = keys[k + 3];
        #pragma unroll
        for (int e = 0; e < 4; ++e) {
            c[e] += (int)(k0 > kk[e]);
            c[e] += (int)(k1 > kk[e]);
            c[e] += (int)(k2 > kk[e]);
            c[e] += (int)(k3 > kk[e]);
        }
    }
    __syncthreads();                      // keys fully read before ss scatter
    // scatter into sorted order (regB)
    ss[c[0]] = xq.x; ss[c[1]] = xq.y; ss[c[2]] = xq.z; ss[c[3]] = xq.w;
    __syncthreads();

    // ---- phase 2a: y[i] = s[i] + (i - 512), in place (centered) -----------
    float4 yq;
    {
        const float4 sq = reinterpret_cast<const float4*>(ss)[t];
        yq.x = sq.x + (float)(j0 - 512);
        yq.y = sq.y + (float)(j0 - 511);
        yq.z = sq.z + (float)(j0 - 510);
        yq.w = sq.w + (float)(j0 - 509);
        reinterpret_cast<float4*>(yv)[t] = yq;   // same region, own chunk
    }
    __syncthreads();

    // ---- phase 2b: descent flags + thread-local inclusive scans -----------
    const float ye[4] = {yq.x, yq.y, yq.z, yq.w};
    int    fl[4];          // raw flags
    int    lf[4];          // local inclusive flag scan
    double lys[4];         // local inclusive y scan
    {
        float prev = (j0 == 0) ? -1.0e30f : yv[j0 - 1];
        double accy = 0.0; int accf = 0;
        #pragma unroll
        for (int e = 0; e < 4; ++e) {
            const int f = (prev > ye[e]) ? 1 : 0;   // strict descent = run start
            prev = ye[e];
            fl[e] = f;
            accf += f;             lf[e]  = accf;
            accy += (double)ye[e]; lys[e] = accy;
        }
    }
    // wave-level inclusive scan of thread totals
    double vy = lys[3]; int vf = lf[3];
    #pragma unroll
    for (int off = 1; off < 64; off <<= 1) {
        const double oy = __shfl_up(vy, off);
        const int    of = __shfl_up(vf, off);
        if (lane >= off) { vy += oy; vf += of; }
    }
    if (lane == 63) { wsumD[wid] = vy; wsumI[wid] = vf; }
    __syncthreads();
    // cross-wave offsets, per-element inclusive values (csum = regA: keys dead)
    {
        double basey = vy - lys[3]; int basef = vf - lf[3];
        for (int w = 0; w < wid; ++w) { basey += wsumD[w]; basef += wsumI[w]; }
        #pragma unroll
        for (int e = 0; e < 4; ++e) {
            const int p   = j0 + e;
            const int seg = basef + lf[e];
            segid[p] = (uint16_t)seg;
            csum[p]  = basey + lys[e];
            if (fl[e]) run_start[seg] = (uint16_t)p;   // unique writer per seg
        }
        if (t == 0) run_start[0] = 0;
    }
    __syncthreads();

    // ---- phase 2c: PAV over runs (thread 0; R tiny for near-monotone y) ---
    if (t == 0) {
        const int R = (int)segid[N - 1] + 1;
        run_start[R] = (uint16_t)N;
        int sp = 0;
        for (int r = 0; r < R; ++r) {
            const int a   = (int)run_start[r];
            const int bnd = (int)run_start[r + 1];
            double s = csum[bnd - 1] - ((a > 0) ? csum[a - 1] : 0.0);
            int    cc = bnd - a;
            int    nr = 1;
            // pool while top block's mean < new block's mean
            while (sp > 0) {
                const uint32_t cr  = stk_cr[sp - 1];
                const int      tc  = (int)(cr & 0xFFFFu);
                if (!(s * (double)tc > stk_sum[sp - 1] * (double)cc)) break;
                s  += stk_sum[sp - 1];
                cc += tc;
                nr += (int)(cr >> 16);
                --sp;
            }
            stk_sum[sp] = s;
            stk_cr[sp]  = (uint32_t)cc | ((uint32_t)nr << 16);
            ++sp;
        }
        int rc = 0;
        for (int e2 = 0; e2 < sp; ++e2) {
            const uint32_t cr = stk_cr[e2];
            const float m = (float)(stk_sum[e2] / (double)(cr & 0xFFFFu));
            const int   nr = (int)(cr >> 16);
            for (int q2 = 0; q2 < nr; ++q2) run_mean[rc++] = m;  // regB: yv dead
        }
    }
    __syncthreads();

    // ---- write ranks, then signal (release orders the 4 KB of stores) -----
    float4 r4;
    r4.x = vv[0] - run_mean[segid[c[0]]] + 512.0f;
    r4.y = vv[1] - run_mean[segid[c[1]]] + 512.0f;
    r4.z = vv[2] - run_mean[segid[c[2]]] + 512.0f;
    r4.w = vv[3] - run_mean[segid[c[3]]] + 512.0f;
    reinterpret_cast<float4*>(ranks + b * N)[t] = r4;

    __syncthreads();   // all threads' rank stores complete (vmcnt drain)
    if (t == 0)
        __hip_atomic_fetch_add(counter, 1, __ATOMIC_RELEASE,
                               __HIP_MEMORY_SCOPE_AGENT);
}

extern "C" void kernel_launch(void* const* d_in, const int* in_sizes, int n_in,
                              void* d_out, int out_size, void* d_ws, size_t ws_size,
                              hipStream_t stream) {
    const float* x = (const float*)d_in[0];
    float* out = (float*)d_out;
    float* ranks = (float*)d_ws;                      // 32K floats = 128 KB
    int* counter = (int*)((float*)d_ws + TOTROWS + 16); // own cacheline past ranks

    init_kernel<<<1, 64, 0, stream>>>(counter);
    fused_kernel<<<BATCH + NFILL, 256, 0, stream>>>(x, out, ranks, counter);
}

// Round 10
// 140.883 us; speedup vs baseline: 1.2054x; 1.2054x over previous
//
#include <hip/hip_runtime.h>
#include <stdint.h>

#define N 1024
#define BATCH 32
#define NFILL 2048   // fill blocks: 2048 x 64 KiB span = 128 MiB output

// ---------------------------------------------------------------------------
// Fused kernel  (R8 verified optimum — session best, reverted after R9's
// in-kernel-sync experiment regressed ~29 us).
//   Blocks [BATCH, BATCH+NFILL): zero-fill the 128 MiB output with PLAIN
//     cached dwordx4 stores (A/B R6/R7 vs R8: plain > nontemporal by ~3 us;
//     rocclr's own 6.6 TB/s fill uses plain stores). NO fences/atomics in
//     either direction: R2 (producer release) collapsed store BW 9x; R9
//     (consumer acquire-poll) lost ~30 us to cross-XCD snoop traffic on the
//     poll line. The kernel boundary is the only cheap device-wide ordering
//     primitive on CDNA4 — scatter runs as a second kernel.
//   Blocks [0, BATCH): one block per batch row — verified R3 rank pipeline;
//     small-LDS layout (uint16 segid/run_start, phase-disjoint unions).
// ---------------------------------------------------------------------------
__global__ __launch_bounds__(256) void fused_kernel(const float* __restrict__ x,
                                                    float* __restrict__ out,
                                                    float* __restrict__ ranks) {
    if (blockIdx.x >= BATCH) {
        // ---- zero-fill branch: contiguous 64 KiB span per block -----------
        const int fid = blockIdx.x - BATCH;
        float4* o = reinterpret_cast<float4*>(out) + (size_t)fid * 4096 + threadIdx.x;
        const float4 z = make_float4(0.0f, 0.0f, 0.0f, 0.0f);
        #pragma unroll
        for (int i = 0; i < 16; ++i)
            o[i * 256] = z;
        return;
    }

    // ---- rank branch (one block per batch row) ----------------------------
    // Region A (8K): keys (u64, phase 1) -> csum (double, phase 2b+).
    //   Last keys read and first csum write are separated by >=2 barriers.
    // Region B (4K): ss (phase 1-2a) -> yv in-place (2a-2b) -> run_mean (PAV+).
    __shared__ double   regA[N];
    __shared__ float    regB[N];
    __shared__ uint16_t segid[N];       // run id per sorted position (<=1023)
    __shared__ uint16_t run_start[N+1]; // run boundary positions (<=1024)
    __shared__ double   stk_sum[N];     // PAV stack: block sums
    __shared__ uint32_t stk_cr[N];      // PAV stack: cnt (low16) | runs (high16)
    __shared__ double   wsumD[4];
    __shared__ int      wsumI[4];

    uint64_t* keys     = reinterpret_cast<uint64_t*>(regA);
    double*   csum     = regA;
    float*    ss       = regB;
    float*    yv       = regB;
    float*    run_mean = regB;

    const int b = blockIdx.x;
    const int t = threadIdx.x;
    const int j0 = t << 2;
    const int lane = t & 63;
    const int wid = t >> 6;

    // ---- phase 1: load row, build keys, count positions in-block ----------
    const float4 xq = reinterpret_cast<const float4*>(x + b * N)[t];
    const float vv[4] = {xq.x, xq.y, xq.z, xq.w};
    uint64_t kk[4];
    {
        #pragma unroll
        for (int e = 0; e < 4; ++e) {
            uint32_t u = __float_as_uint(vv[e]);
            u ^= (u & 0x80000000u) ? 0xFFFFFFFFu : 0x80000000u;  // monotone map
            // descending, stable: position = #{k : key_k > key_j}
            kk[e] = (((uint64_t)u) << 10) | (uint64_t)(1023 - (j0 + e));
            keys[j0 + e] = kk[e];
        }
    }
    __syncthreads();

    int c[4] = {0, 0, 0, 0};
    for (int k = 0; k < N; k += 4) {
        const uint64_t k0 = keys[k];       // broadcast reads, conflict-free
        const uint64_t k1 = keys[k + 1];
        const uint64_t k2 = keys[k + 2];
        const uint64_t k3 = keys[k + 3];
        #pragma unroll
        for (int e = 0; e < 4; ++e) {
            c[e] += (int)(k0 > kk[e]);
            c[e] += (int)(k1 > kk[e]);
            c[e] += (int)(k2 > kk[e]);
            c[e] += (int)(k3 > kk[e]);
        }
    }
    __syncthreads();                      // keys fully read before ss scatter
    // scatter into sorted order (regB)
    ss[c[0]] = xq.x; ss[c[1]] = xq.y; ss[c[2]] = xq.z; ss[c[3]] = xq.w;
    __syncthreads();

    // ---- phase 2a: y[i] = s[i] + (i - 512), in place (centered) -----------
    float4 yq;
    {
        const float4 sq = reinterpret_cast<const float4*>(ss)[t];
        yq.x = sq.x + (float)(j0 - 512);
        yq.y = sq.y + (float)(j0 - 511);
        yq.z = sq.z + (float)(j0 - 510);
        yq.w = sq.w + (float)(j0 - 509);
        reinterpret_cast<float4*>(yv)[t] = yq;   // same region, own chunk
    }
    __syncthreads();

    // ---- phase 2b: descent flags + thread-local inclusive scans -----------
    const float ye[4] = {yq.x, yq.y, yq.z, yq.w};
    int    fl[4];          // raw flags
    int    lf[4];          // local inclusive flag scan
    double lys[4];         // local inclusive y scan
    {
        float prev = (j0 == 0) ? -1.0e30f : yv[j0 - 1];
        double accy = 0.0; int accf = 0;
        #pragma unroll
        for (int e = 0; e < 4; ++e) {
            const int f = (prev > ye[e]) ? 1 : 0;   // strict descent = run start
            prev = ye[e];
            fl[e] = f;
            accf += f;             lf[e]  = accf;
            accy += (double)ye[e]; lys[e] = accy;
        }
    }
    // wave-level inclusive scan of thread totals
    double vy = lys[3]; int vf = lf[3];
    #pragma unroll
    for (int off = 1; off < 64; off <<= 1) {
        const double oy = __shfl_up(vy, off);
        const int    of = __shfl_up(vf, off);
        if (lane >= off) { vy += oy; vf += of; }
    }
    if (lane == 63) { wsumD[wid] = vy; wsumI[wid] = vf; }
    __syncthreads();
    // cross-wave offsets, per-element inclusive values (csum = regA: keys dead)
    {
        double basey = vy - lys[3]; int basef = vf - lf[3];
        for (int w = 0; w < wid; ++w) { basey += wsumD[w]; basef += wsumI[w]; }
        #pragma unroll
        for (int e = 0; e < 4; ++e) {
            const int p   = j0 + e;
            const int seg = basef + lf[e];
            segid[p] = (uint16_t)seg;
            csum[p]  = basey + lys[e];
            if (fl[e]) run_start[seg] = (uint16_t)p;   // unique writer per seg
        }
        if (t == 0) run_start[0] = 0;
    }
    __syncthreads();

    // ---- phase 2c: PAV over runs (thread 0; R tiny for near-monotone y) ---
    if (t == 0) {
        const int R = (int)segid[N - 1] + 1;
        run_start[R] = (uint16_t)N;
        int sp = 0;
        for (int r = 0; r < R; ++r) {
            const int a   = (int)run_start[r];
            const int bnd = (int)run_start[r + 1];
            double s = csum[bnd - 1] - ((a > 0) ? csum[a - 1] : 0.0);
            int    cc = bnd - a;
            int    nr = 1;
            // pool while top block's mean < new block's mean
            while (sp > 0) {
                const uint32_t cr  = stk_cr[sp - 1];
                const int      tc  = (int)(cr & 0xFFFFu);
                if (!(s * (double)tc > stk_sum[sp - 1] * (double)cc)) break;
                s  += stk_sum[sp - 1];
                cc += tc;
                nr += (int)(cr >> 16);
                --sp;
            }
            stk_sum[sp] = s;
            stk_cr[sp]  = (uint32_t)cc | ((uint32_t)nr << 16);
            ++sp;
        }
        int rc = 0;
        for (int e2 = 0; e2 < sp; ++e2) {
            const uint32_t cr = stk_cr[e2];
            const float m = (float)(stk_sum[e2] / (double)(cr & 0xFFFFu));
            const int   nr = (int)(cr >> 16);
            for (int q2 = 0; q2 < nr; ++q2) run_mean[rc++] = m;  // regB: yv dead
        }
    }
    __syncthreads();

    // ---- write ranks: ranks[j] = x[j] - (sol - 512) -----------------------
    float4 r4;
    r4.x = vv[0] - run_mean[segid[c[0]]] + 512.0f;
    r4.y = vv[1] - run_mean[segid[c[1]]] + 512.0f;
    r4.z = vv[2] - run_mean[segid[c[2]]] + 512.0f;
    r4.w = vv[3] - run_mean[segid[c[3]]] + 512.0f;
    reinterpret_cast<float4*>(ranks + b * N)[t] = r4;
}

// ---------------------------------------------------------------------------
// Kernel S: scatter the <=2 nonzeros per output row (verified R0-R8).
//   out[b,j,i] = relu(1 - |r - (i+1)|) is a width-2 triangle: nonzero only at
//   i+1 = floor(r) (value 1-frac) and i+1 = floor(r)+1 (value frac).
//   Numerically identical to the dense per-element computation.
//   One thread per (b,j) row; coalesced rank load, <=2 scattered 4 B stores.
// ---------------------------------------------------------------------------
__global__ __launch_bounds__(256) void scatter_kernel(const float* __restrict__ ranks,
                                                      float* __restrict__ out) {
    const int row = blockIdx.x * 256 + threadIdx.x;   // row = b*N + j, 32768 rows
    const float r = ranks[row];
    const float f = floorf(r);
    const int   i1 = (int)f;            // nonzero at i+1 == i1 and i+1 == i1+1
    const float frac = r - f;
    float* o = out + (size_t)row * N;
    if (i1 >= 1 && i1 <= N) o[i1 - 1] = 1.0f - frac;
    if (i1 >= 0 && i1 <  N) o[i1]     = frac;
}

extern "C" void kernel_launch(void* const* d_in, const int* in_sizes, int n_in,
                              void* d_out, int out_size, void* d_ws, size_t ws_size,
                              hipStream_t stream) {
    const float* x = (const float*)d_in[0];
    float* out = (float*)d_out;
    float* ranks = (float*)d_ws;                      // 32K floats = 128 KB

    fused_kernel<<<BATCH + NFILL, 256, 0, stream>>>(x, out, ranks);
    scatter_kernel<<<(BATCH * N) / 256, 256, 0, stream>>>(ranks, out);
}